// Round 6
// baseline (19271.698 us; speedup 1.0000x reference)
//
#include <hip/hip_runtime.h>

typedef _Float16 half8 __attribute__((ext_vector_type(8)));
typedef float f32x4 __attribute__((ext_vector_type(4)));

#define GRIDN 192
#define NTICKS 514
#define TT 512
#define HH 1024

// MFMA with B operand pinned in AGPRs (gfx950 unified RF: MFMA reads A/B from AGPR).
#define MFMA_F16_AB(acc_, a_, b_) \
  asm("v_mfma_f32_16x16x32_f16 %0, %1, %2, %0" : "+v"(acc_) : "v"(a_), "a"(b_))

// Tie-copy a loaded value into an AGPR-class vreg whose DEF is an inline asm.
// With low arch pressure (this round's point) the live range stays resident.
#define PIN_AGPR(dst_, src_) asm("" : "=a"(dst_) : "0"(src_))

__device__ __forceinline__ int kfrag(int l, int j) {
  // consistent A/B fragment k mapping (two K=16 halves, 4-element chunks per 16-lane group)
  return ((j >> 2) << 4) + (((l >> 4) & 3) << 2) + (j & 3);
}

__device__ __forceinline__ size_t fragoff(int m, int k, int KBv) {
  int rt = m >> 4, mm = m & 15, kb = k >> 5, kk = k & 31;
  int lp = mm | ((kk & 12) << 2);           // lane'
  int jp = ((kk >> 4) << 2) | (kk & 3);     // elem'
  return ((size_t)(rt * KBv + kb) * 512) + (size_t)lp * 8 + jp;
}

__device__ __forceinline__ float sigmoidf_(float x) { return 1.0f / (1.0f + __expf(-x)); }
__device__ __forceinline__ float tanhf_(float x)    { return 2.0f / (1.0f + __expf(-2.0f * x)) - 1.0f; }

// ---------------- weight pack: W[k][4096] -> frag layout [cg][kb][gate][lane*8+j] (f16) ---------
__global__ __launch_bounds__(256) void pack_b_kernel(const float* __restrict__ W,
                                                     _Float16* __restrict__ dst, int KB) {
  int e = blockIdx.x * 256 + threadIdx.x;
  int total = 64 * KB * 4 * 512;
  if (e >= total) return;
  int j = e & 7, l = (e >> 3) & 63, nt = (e >> 9) & 3;
  int tmp = e >> 11;
  int kb = tmp % KB, cg = tmp / KB;
  int k = kb * 32 + kfrag(l, j);
  int col = nt * 1024 + cg * 16 + (l & 15);
  dst[e] = (_Float16)W[(size_t)k * 4096 + col];
}

// ---------------- x pack: struct[b][t][d] -> frag layout [t][rt][kb][lane*8+j] (f16) ------------
__global__ __launch_bounds__(256) void pack_x_kernel(const float* __restrict__ x,
                                                     _Float16* __restrict__ dst) {
  int e = blockIdx.x * 256 + threadIdx.x;
  if (e >= TT * 4 * 8 * 512) return;
  int j = e & 7, l = (e >> 3) & 63;
  int tmp = e >> 9;
  int kb = tmp & 7; tmp >>= 3;
  int rt = tmp & 3; int t = tmp >> 2;
  int b = rt * 16 + (l & 15);
  int d = kb * 32 + kfrag(l, j);
  dst[e] = (_Float16)x[((size_t)b * TT + t) * 256 + d];
}

// ---------------- grid barrier: 8 padded monotonic counters, leaderless ------------------------
__device__ __forceinline__ void grid_barrier(unsigned* bar, int tick) {
  __syncthreads();
  if (threadIdx.x == 0) {
    __threadfence();  // release: publish this block's A-frag stores device-wide
    __hip_atomic_fetch_add(&bar[32 * (blockIdx.x & 7)], 1u, __ATOMIC_RELAXED,
                           __HIP_MEMORY_SCOPE_AGENT);
  }
  if (threadIdx.x < 64) {
    const unsigned target = (unsigned)(tick + 1) * 24u;  // 192/8 arrivals per counter per tick
    const int lane = threadIdx.x;
    for (;;) {
      unsigned v = target;
      if (lane < 8)
        v = __hip_atomic_load(&bar[32 * lane], __ATOMIC_RELAXED, __HIP_MEMORY_SCOPE_AGENT);
      if (__all(v >= target)) break;
      __builtin_amdgcn_s_sleep(2);
    }
    __threadfence();  // acquire: inv — drop stale A lines from this XCD's L2 (once per tick)
  }
  __syncthreads();
}

// ---------------- persistent pipelined cell loop --------------------------------------------
// 8 warps = 4 gates (N-split) x 2 K-halves. Per warp: KBW kb x 1 gate weights in AGPR
// (128 AGPR for cells 1/2, 80 for cell 0). Gate exchange via 32 KiB LDS.
template <int CELL, int KBW, int AKB>
__device__ __forceinline__ void run_cell(float (*part)[4][4][64][4],
                                         const _Float16* __restrict__ Bf,
                                         const _Float16* __restrict__ Ax,
                                         _Float16* Aown, _Float16* Anext,
                                         const float* __restrict__ bias,
                                         float* __restrict__ h3out, unsigned* bar) {
  const int cg   = blockIdx.x & 63;
  const int tid  = threadIdx.x;
  const int wid  = tid >> 6;     // 0..7
  const int lane = tid & 63;
  const int nt   = wid & 3;      // gate owned by this warp
  const int kh   = wid >> 2;     // K-half owned by this warp
  const int KBTOT = (CELL == 0) ? 40 : 64;
  const int kb0   = kh * KBW;

  // elementwise ownership: cells (m, colc) with m = (tid>>4) + e*32, colc = tid&15
  const int colc = tid & 15;
  const int hcol = cg * 16 + colc;
  float bvv[4];
#pragma unroll
  for (int g = 0; g < 4; ++g) bvv[g] = bias[g * HH + hcol];

  // ---- preload this warp's weight slice ONCE; pin in AGPRs ----
  half8 wa[KBW];
  const _Float16* Bbase = Bf + (size_t)cg * KBTOT * 4 * 512 + (size_t)lane * 8;
#pragma unroll
  for (int kk = 0; kk < KBW; ++kk) {
    half8 v = *(const half8*)(Bbase + ((size_t)(kb0 + kk) * 4 + nt) * 512);
    PIN_AGPR(wa[kk], v);
  }

  // ---- persistent cell state in registers: thread owns cells (m0, colc), (m0+32, colc) ----
  float cs0 = 0.f, cs1 = 0.f, hs0 = 0.f, hs1 = 0.f;

  for (int tick = 0; tick < NTICKS; ++tick) {
    const int t = tick - CELL;
    if (t >= 0 && t < TT) {
      const int wpar = tick & 1, rpar = wpar ^ 1;
      const _Float16* Ard = Aown + (size_t)rpar * 4 * AKB * 512 + (size_t)lane * 8;
      const _Float16* Axt = Ax + (size_t)t * 4 * 8 * 512 + (size_t)lane * 8;

      auto aptr = [&](int kk, int rt) -> const _Float16* {
        int kb = kb0 + kk;
        if (CELL == 0 && kb >= 32) return Axt + ((size_t)rt * 8 + (kb - 32)) * 512;
        return Ard + ((size_t)rt * AKB + kb) * 512;
      };

      // 1-ahead A prefetch ring (all indices compile-time)
      half8 av[2][4];
#pragma unroll
      for (int rt = 0; rt < 4; ++rt) av[0][rt] = *(const half8*)aptr(0, rt);

      f32x4 acc[4];
#pragma unroll
      for (int rt = 0; rt < 4; ++rt) acc[rt] = (f32x4){0.f, 0.f, 0.f, 0.f};

#pragma unroll
      for (int kk = 0; kk < KBW; ++kk) {
        if (kk + 1 < KBW) {
#pragma unroll
          for (int rt = 0; rt < 4; ++rt)
            av[(kk + 1) & 1][rt] = *(const half8*)aptr(kk + 1, rt);
        }
#pragma unroll
        for (int rt = 0; rt < 4; ++rt)
          MFMA_F16_AB(acc[rt], av[kk & 1][rt], wa[kk]);
      }
      // guard asm-MFMA -> DS read-after-write (hazard recognizer can't see into asm)
      asm volatile("s_nop 7\n\ts_nop 7");

      // gate exchange: warp (nt,kh) publishes its partial pre-activations
#pragma unroll
      for (int rt = 0; rt < 4; ++rt)
        *(f32x4*)&part[kh][nt][rt][lane][0] = acc[rt];
      __syncthreads();

      // elementwise: 1024 cells over 512 threads (2 each, fixed -> reg state)
#pragma unroll
      for (int e = 0; e < 2; ++e) {
        const int m  = (tid >> 4) + e * 32;
        const int rt = m >> 4, q = (m >> 2) & 3, r = m & 3;
        const int lp = q * 16 + colc;
        float pre[4];
#pragma unroll
        for (int g = 0; g < 4; ++g)
          pre[g] = part[0][g][rt][lp][r] + part[1][g][rt][lp][r] + bvv[g];
        float sf = sigmoidf_(pre[0]), si = sigmoidf_(pre[1]), so = sigmoidf_(pre[2]);
        float tg = tanhf_(pre[3]);
        float c_old = e ? cs1 : cs0, h_old = e ? hs1 : hs0;
        float c0 = sf * c_old + si * tg;
        float h0 = so * tanhf_(c0);
        float cn = 0.9f * c0 + 0.1f * c_old;
        float hn = 0.9f * h0 + 0.1f * h_old;
        if (e) { cs1 = cn; hs1 = hn; } else { cs0 = cn; hs0 = hn; }
        _Float16 hv = (_Float16)hn;
        Aown[(size_t)wpar * 4 * AKB * 512 + fragoff(m, hcol, AKB)] = hv;
        if (CELL < 2) Anext[(size_t)wpar * 4 * 64 * 512 + fragoff(m, 1024 + hcol, 64)] = hv;
        if (CELL == 2 && t == TT - 1) h3out[m * HH + hcol] = hn;
      }
    }

    if (tick < NTICKS - 1) grid_barrier(bar, tick);
  }
}

__global__ __launch_bounds__(512, 2) void lstm_coop(
    const _Float16* __restrict__ Bf1, const _Float16* __restrict__ Bf2,
    const _Float16* __restrict__ Bf3, const _Float16* __restrict__ Ax,
    _Float16* A1h, _Float16* A2v, _Float16* A3v, float* h3,
    const float* __restrict__ bb1, const float* __restrict__ bb2, const float* __restrict__ bb3,
    unsigned* bar) {
  __shared__ float part[2][4][4][64][4];  // 32 KiB gate-exchange, shared by all cell paths
  const int cell = blockIdx.x >> 6;
  if (cell == 0)
    run_cell<0, 20, 32>(part, Bf1, Ax, A1h, A2v, bb1, nullptr, bar);
  else if (cell == 1)
    run_cell<1, 32, 64>(part, Bf2, Ax, A2v, A3v, bb2, nullptr, bar);
  else
    run_cell<2, 32, 64>(part, Bf3, Ax, A3v, nullptr, bb3, h3, bar);
}

// ---------------- final FC + ELU: out[b][c] = elu(h3[b,:]·fc_w[c,:] + fc_b[c]) ------------------
__global__ __launch_bounds__(256) void fc_kernel(const float* __restrict__ h3,
                                                 const float* __restrict__ fcw,
                                                 const float* __restrict__ fcb,
                                                 float* __restrict__ out) {
  int wid = (blockIdx.x * 256 + threadIdx.x) >> 6;
  int lane = threadIdx.x & 63;
  if (wid >= 64 * 128) return;
  int b = wid >> 7, cc = wid & 127;
  float s = 0.f;
#pragma unroll
  for (int i = 0; i < 16; ++i) {
    int k = i * 64 + lane;
    s += h3[b * HH + k] * fcw[cc * HH + k];
  }
#pragma unroll
  for (int o = 32; o; o >>= 1) s += __shfl_xor(s, o, 64);
  if (lane == 0) {
    s += fcb[cc];
    out[b * 128 + cc] = s > 0.f ? s : (__expf(s) - 1.0f);
  }
}

extern "C" void kernel_launch(void* const* d_in, const int* in_sizes, int n_in,
                              void* d_out, int out_size, void* d_ws, size_t ws_size,
                              hipStream_t stream) {
  const float* xs  = (const float*)d_in[0];
  const float* W1  = (const float*)d_in[1];
  const float* b1  = (const float*)d_in[2];
  const float* W2  = (const float*)d_in[3];
  const float* b2  = (const float*)d_in[4];
  const float* W3  = (const float*)d_in[5];
  const float* b3  = (const float*)d_in[6];
  const float* fcw = (const float*)d_in[7];
  const float* fcb = (const float*)d_in[8];
  float* out = (float*)d_out;

  char* p = (char*)d_ws;
  auto alloc = [&](size_t bytes) {
    char* r = p;
    p += (bytes + 255) & ~(size_t)255;
    return r;
  };

  // ---- zero-init region (re-zeroed every replay) ----
  char* zbase = p;
  _Float16* A1h = (_Float16*)alloc((size_t)2 * 4 * 32 * 512 * 2);
  _Float16* A2v = (_Float16*)alloc((size_t)2 * 4 * 64 * 512 * 2);
  _Float16* A3v = (_Float16*)alloc((size_t)2 * 4 * 64 * 512 * 2);
  unsigned* bar = (unsigned*)alloc(1024);
  size_t zbytes = (size_t)(p - zbase);

  // ---- fully-overwritten region ----
  float* h3 = (float*)alloc((size_t)64 * 1024 * 4);
  _Float16* Bf1 = (_Float16*)alloc((size_t)64 * 40 * 4 * 512 * 2);
  _Float16* Bf2 = (_Float16*)alloc((size_t)64 * 64 * 4 * 512 * 2);
  _Float16* Bf3 = (_Float16*)alloc((size_t)64 * 64 * 4 * 512 * 2);
  _Float16* Axp = (_Float16*)alloc((size_t)TT * 4 * 8 * 512 * 2);

  (void)hipMemsetAsync(zbase, 0, zbytes, stream);

  {
    int tot1 = 64 * 40 * 4 * 512, tot23 = 64 * 64 * 4 * 512;
    pack_b_kernel<<<(tot1 + 255) / 256, 256, 0, stream>>>(W1, Bf1, 40);
    pack_b_kernel<<<(tot23 + 255) / 256, 256, 0, stream>>>(W2, Bf2, 64);
    pack_b_kernel<<<(tot23 + 255) / 256, 256, 0, stream>>>(W3, Bf3, 64);
    int totx = TT * 4 * 8 * 512;
    pack_x_kernel<<<(totx + 255) / 256, 256, 0, stream>>>(xs, Axp);
  }

  lstm_coop<<<GRIDN, 512, 0, stream>>>(Bf1, Bf2, Bf3, Axp, A1h, A2v, A3v, h3,
                                       b1, b2, b3, bar);

  fc_kernel<<<(64 * 128 * 64 + 255) / 256, 256, 0, stream>>>(h3, fcw, fcb, out);
}

// Round 7
// 9880.969 us; speedup vs baseline: 1.9504x; 1.9504x over previous
//
#include <hip/hip_runtime.h>

typedef _Float16 half8 __attribute__((ext_vector_type(8)));
typedef float f32x4 __attribute__((ext_vector_type(4)));

#define GRIDN 192
#define NTICKS 514
#define TT 512
#define HH 1024

// MFMA, B operand in AGPR ("a") — for the pinned weight units.
#define MFMA_F16_AB(acc_, a_, b_) \
  asm("v_mfma_f32_16x16x32_f16 %0, %1, %2, %0" : "+v"(acc_) : "v"(a_), "a"(b_))
// MFMA, B operand in arch VGPR ("v") — for LDS-staged weight units.
#define MFMA_F16_AV(acc_, a_, b_) \
  asm("v_mfma_f32_16x16x32_f16 %0, %1, %2, %0" : "+v"(acc_) : "v"(a_), "v"(b_))

// Tie-copy a loaded value into an AGPR-class vreg whose DEF is an inline asm
// (non-rematerializable). With ~120 regs of slack this stays resident.
#define PIN_AGPR(dst_, src_) asm("" : "=a"(dst_) : "0"(src_))

__device__ __forceinline__ int kfrag(int l, int j) {
  return ((j >> 2) << 4) + (((l >> 4) & 3) << 2) + (j & 3);
}

__device__ __forceinline__ size_t fragoff(int m, int k, int KBv) {
  int rt = m >> 4, mm = m & 15, kb = k >> 5, kk = k & 31;
  int lp = mm | ((kk & 12) << 2);
  int jp = ((kk >> 4) << 2) | (kk & 3);
  return ((size_t)(rt * KBv + kb) * 512) + (size_t)lp * 8 + jp;
}

__device__ __forceinline__ float sigmoidf_(float x) { return 1.0f / (1.0f + __expf(-x)); }
__device__ __forceinline__ float tanhf_(float x)    { return 2.0f / (1.0f + __expf(-2.0f * x)) - 1.0f; }

// ---------------- weight pack: W[k][4096] -> frag layout [cg][kb][gate][lane*8+j] (f16) ---------
__global__ __launch_bounds__(256) void pack_b_kernel(const float* __restrict__ W,
                                                     _Float16* __restrict__ dst, int KB) {
  int e = blockIdx.x * 256 + threadIdx.x;
  int total = 64 * KB * 4 * 512;
  if (e >= total) return;
  int j = e & 7, l = (e >> 3) & 63, nt = (e >> 9) & 3;
  int tmp = e >> 11;
  int kb = tmp % KB, cg = tmp / KB;
  int k = kb * 32 + kfrag(l, j);
  int col = nt * 1024 + cg * 16 + (l & 15);
  dst[e] = (_Float16)W[(size_t)k * 4096 + col];
}

// ---------------- x pack: struct[b][t][d] -> frag layout [t][rt][kb][lane*8+j] (f16) ------------
__global__ __launch_bounds__(256) void pack_x_kernel(const float* __restrict__ x,
                                                     _Float16* __restrict__ dst) {
  int e = blockIdx.x * 256 + threadIdx.x;
  if (e >= TT * 4 * 8 * 512) return;
  int j = e & 7, l = (e >> 3) & 63;
  int tmp = e >> 9;
  int kb = tmp & 7; tmp >>= 3;
  int rt = tmp & 3; int t = tmp >> 2;
  int b = rt * 16 + (l & 15);
  int d = kb * 32 + kfrag(l, j);
  dst[e] = (_Float16)x[((size_t)b * TT + t) * 256 + d];
}

// ---------------- grid barrier: 8 padded monotonic counters, leaderless ------------------------
__device__ __forceinline__ void grid_barrier(unsigned* bar, int tick) {
  __syncthreads();
  if (threadIdx.x == 0) {
    __threadfence();  // release: publish this block's A-frag stores device-wide
    __hip_atomic_fetch_add(&bar[32 * (blockIdx.x & 7)], 1u, __ATOMIC_RELAXED,
                           __HIP_MEMORY_SCOPE_AGENT);
  }
  if (threadIdx.x < 64) {
    const unsigned target = (unsigned)(tick + 1) * 24u;
    const int lane = threadIdx.x;
    for (;;) {
      unsigned v = target;
      if (lane < 8)
        v = __hip_atomic_load(&bar[32 * lane], __ATOMIC_RELAXED, __HIP_MEMORY_SCOPE_AGENT);
      if (__all(v >= target)) break;
      __builtin_amdgcn_s_sleep(2);
    }
    __threadfence();  // acquire: inv — drop stale A lines (weights immune: AGPR+LDS)
  }
  __syncthreads();
}

// ---------------- persistent pipelined cell loop --------------------------------------------
// 4 warps K-split (round-5 mapping, no A redundancy). Weight slice per warp = 4*KBW units
// (1 unit = half8/lane): first UA units pinned in AGPR, rest staged once into LDS.
template <int CELL, int KBW, int AKB, int UA>
__device__ __forceinline__ void run_cell(float (*red)[16][64][4],
                                         _Float16 (*wlds)[20][512],
                                         const _Float16* __restrict__ Bf,
                                         const _Float16* __restrict__ Ax,
                                         _Float16* Aown, _Float16* Anext,
                                         const float* __restrict__ bias,
                                         float* __restrict__ h3out, unsigned* bar) {
  const int cg   = blockIdx.x & 63;
  const int warp = threadIdx.x >> 6;
  const int lane = threadIdx.x & 63;
  const int KBTOT = (CELL == 0) ? 40 : 64;
  const int kb0   = warp * KBW;
  const int hcol  = cg * 16 + (lane & 15);

  float bv[4];
#pragma unroll
  for (int nt = 0; nt < 4; ++nt) bv[nt] = bias[nt * HH + hcol];

  const _Float16* Bbase = Bf + (size_t)cg * KBTOT * 4 * 512 + (size_t)lane * 8;

  // ---- stage overflow weight units into LDS (once; immune to inv & regalloc) ----
  if (UA < 4 * KBW) {
#pragma unroll
    for (int u = UA; u < 4 * KBW; ++u) {
      int kk2 = u >> 2, nt2 = u & 3;
      *(half8*)&wlds[warp][u - UA][lane * 8] =
          *(const half8*)(Bbase + ((size_t)(kb0 + kk2) * 4 + nt2) * 512);
    }
  }

  // ---- pin the first UA units in AGPRs ----
  half8 wa[UA];
#pragma unroll
  for (int u = 0; u < UA; ++u) {
    int kk2 = u >> 2, nt2 = u & 3;
    half8 v = *(const half8*)(Bbase + ((size_t)(kb0 + kk2) * 4 + nt2) * 512);
    PIN_AGPR(wa[u], v);
  }

  // ---- persistent cell state in registers ----
  f32x4 creg = (f32x4){0.f, 0.f, 0.f, 0.f};
  f32x4 hreg = (f32x4){0.f, 0.f, 0.f, 0.f};

  for (int tick = 0; tick < NTICKS; ++tick) {
    const int t = tick - CELL;
    if (t >= 0 && t < TT) {
      const int wpar = tick & 1, rpar = wpar ^ 1;
      const _Float16* Ard = Aown + (size_t)rpar * 4 * AKB * 512 + (size_t)lane * 8;
      const _Float16* Axt = Ax + (size_t)t * 4 * 8 * 512 + (size_t)lane * 8;

      auto aptr = [&](int kk, int rt) -> const _Float16* {
        int kb = kb0 + kk;
        if (CELL == 0 && kb >= 32) return Axt + ((size_t)rt * 8 + (kb - 32)) * 512;
        return Ard + ((size_t)rt * AKB + kb) * 512;
      };

      // 4-ahead A prefetch, ring of 6 (all indices compile-time)
      half8 av[6][4];
#pragma unroll
      for (int p = 0; p < 4; ++p)
#pragma unroll
        for (int rt = 0; rt < 4; ++rt) av[p][rt] = *(const half8*)aptr(p, rt);

      f32x4 acc[4][4];
#pragma unroll
      for (int a = 0; a < 4; ++a)
#pragma unroll
        for (int b2 = 0; b2 < 4; ++b2) acc[a][b2] = (f32x4){0.f, 0.f, 0.f, 0.f};

#pragma unroll
      for (int kk = 0; kk < KBW; ++kk) {
        if (kk + 4 < KBW) {
#pragma unroll
          for (int rt = 0; rt < 4; ++rt)
            av[(kk + 4) % 6][rt] = *(const half8*)aptr(kk + 4, rt);
        }
#pragma unroll
        for (int nt = 0; nt < 4; ++nt) {
          const int u = kk * 4 + nt;
          if (u < UA) {
#pragma unroll
            for (int rt = 0; rt < 4; ++rt)
              MFMA_F16_AB(acc[rt][nt], av[kk % 6][rt], wa[u < UA ? u : 0]);
          } else {
            half8 b = *(const half8*)&wlds[warp][(u >= UA ? u - UA : 0)][lane * 8];
#pragma unroll
            for (int rt = 0; rt < 4; ++rt)
              MFMA_F16_AV(acc[rt][nt], av[kk % 6][rt], b);
          }
        }
      }
      // guard asm-MFMA -> DS read-after-write (hazard recognizer can't see into asm)
      asm volatile("s_nop 7\n\ts_nop 7");

      // K-split reduction across the 4 warps via LDS
#pragma unroll
      for (int rt = 0; rt < 4; ++rt)
#pragma unroll
        for (int nt = 0; nt < 4; ++nt)
          *(f32x4*)&red[warp][rt * 4 + nt][lane][0] = acc[rt][nt];
      __syncthreads();

      f32x4 sv[4];
#pragma unroll
      for (int nt = 0; nt < 4; ++nt) {
        f32x4 s = *(f32x4*)&red[0][warp * 4 + nt][lane][0];
#pragma unroll
        for (int w2 = 1; w2 < 4; ++w2) s += *(f32x4*)&red[w2][warp * 4 + nt][lane][0];
        sv[nt] = s;
      }

      // elementwise: this warp owns rows m in [16*warp, 16*warp+16), state in registers
#pragma unroll
      for (int r = 0; r < 4; ++r) {
        float fv = sv[0][r] + bv[0];
        float iv = sv[1][r] + bv[1];
        float ov = sv[2][r] + bv[2];
        float gv = sv[3][r] + bv[3];
        int m = warp * 16 + ((lane >> 4) << 2) + r;
        float sf = sigmoidf_(fv), si = sigmoidf_(iv), so = sigmoidf_(ov);
        float tg = tanhf_(gv);
        float c_old = creg[r], h_old = hreg[r];
        float c0 = sf * c_old + si * tg;
        float h0 = so * tanhf_(c0);
        float cn = 0.9f * c0 + 0.1f * c_old;
        float hn = 0.9f * h0 + 0.1f * h_old;
        creg[r] = cn;
        hreg[r] = hn;
        _Float16 hv = (_Float16)hn;
        Aown[(size_t)wpar * 4 * AKB * 512 + fragoff(m, hcol, AKB)] = hv;
        if (CELL < 2) Anext[(size_t)wpar * 4 * 64 * 512 + fragoff(m, 1024 + hcol, 64)] = hv;
        if (CELL == 2 && t == TT - 1) h3out[m * HH + hcol] = hn;
      }
    }

    if (tick < NTICKS - 1) grid_barrier(bar, tick);
  }
}

__global__ __launch_bounds__(256, 1) void lstm_coop(
    const _Float16* __restrict__ Bf1, const _Float16* __restrict__ Bf2,
    const _Float16* __restrict__ Bf3, const _Float16* __restrict__ Ax,
    _Float16* A1h, _Float16* A2v, _Float16* A3v, float* h3,
    const float* __restrict__ bb1, const float* __restrict__ bb2, const float* __restrict__ bb3,
    unsigned* bar) {
  __shared__ float red[4][16][64][4];        // 64 KiB exchange
  __shared__ _Float16 wlds[4][20][512];      // 80 KiB LDS-resident weight units
  const int cell = blockIdx.x >> 6;
  if (cell == 0)
    run_cell<0, 10, 32, 40>(red, wlds, Bf1, Ax, A1h, A2v, bb1, nullptr, bar);
  else if (cell == 1)
    run_cell<1, 16, 64, 44>(red, wlds, Bf2, Ax, A2v, A3v, bb2, nullptr, bar);
  else
    run_cell<2, 16, 64, 44>(red, wlds, Bf3, Ax, A3v, nullptr, bb3, h3, bar);
}

// ---------------- final FC + ELU ----------------------------------------------------------------
__global__ __launch_bounds__(256) void fc_kernel(const float* __restrict__ h3,
                                                 const float* __restrict__ fcw,
                                                 const float* __restrict__ fcb,
                                                 float* __restrict__ out) {
  int wid = (blockIdx.x * 256 + threadIdx.x) >> 6;
  int lane = threadIdx.x & 63;
  if (wid >= 64 * 128) return;
  int b = wid >> 7, cc = wid & 127;
  float s = 0.f;
#pragma unroll
  for (int i = 0; i < 16; ++i) {
    int k = i * 64 + lane;
    s += h3[b * HH + k] * fcw[cc * HH + k];
  }
#pragma unroll
  for (int o = 32; o; o >>= 1) s += __shfl_xor(s, o, 64);
  if (lane == 0) {
    s += fcb[cc];
    out[b * 128 + cc] = s > 0.f ? s : (__expf(s) - 1.0f);
  }
}

extern "C" void kernel_launch(void* const* d_in, const int* in_sizes, int n_in,
                              void* d_out, int out_size, void* d_ws, size_t ws_size,
                              hipStream_t stream) {
  const float* xs  = (const float*)d_in[0];
  const float* W1  = (const float*)d_in[1];
  const float* b1  = (const float*)d_in[2];
  const float* W2  = (const float*)d_in[3];
  const float* b2  = (const float*)d_in[4];
  const float* W3  = (const float*)d_in[5];
  const float* b3  = (const float*)d_in[6];
  const float* fcw = (const float*)d_in[7];
  const float* fcb = (const float*)d_in[8];
  float* out = (float*)d_out;

  char* p = (char*)d_ws;
  auto alloc = [&](size_t bytes) {
    char* r = p;
    p += (bytes + 255) & ~(size_t)255;
    return r;
  };

  // ---- zero-init region (re-zeroed every replay) ----
  char* zbase = p;
  _Float16* A1h = (_Float16*)alloc((size_t)2 * 4 * 32 * 512 * 2);
  _Float16* A2v = (_Float16*)alloc((size_t)2 * 4 * 64 * 512 * 2);
  _Float16* A3v = (_Float16*)alloc((size_t)2 * 4 * 64 * 512 * 2);
  unsigned* bar = (unsigned*)alloc(1024);
  size_t zbytes = (size_t)(p - zbase);

  // ---- fully-overwritten region ----
  float* h3 = (float*)alloc((size_t)64 * 1024 * 4);
  _Float16* Bf1 = (_Float16*)alloc((size_t)64 * 40 * 4 * 512 * 2);
  _Float16* Bf2 = (_Float16*)alloc((size_t)64 * 64 * 4 * 512 * 2);
  _Float16* Bf3 = (_Float16*)alloc((size_t)64 * 64 * 4 * 512 * 2);
  _Float16* Axp = (_Float16*)alloc((size_t)TT * 4 * 8 * 512 * 2);

  (void)hipMemsetAsync(zbase, 0, zbytes, stream);

  {
    int tot1 = 64 * 40 * 4 * 512, tot23 = 64 * 64 * 4 * 512;
    pack_b_kernel<<<(tot1 + 255) / 256, 256, 0, stream>>>(W1, Bf1, 40);
    pack_b_kernel<<<(tot23 + 255) / 256, 256, 0, stream>>>(W2, Bf2, 64);
    pack_b_kernel<<<(tot23 + 255) / 256, 256, 0, stream>>>(W3, Bf3, 64);
    int totx = TT * 4 * 8 * 512;
    pack_x_kernel<<<(totx + 255) / 256, 256, 0, stream>>>(xs, Axp);
  }

  lstm_coop<<<GRIDN, 256, 0, stream>>>(Bf1, Bf2, Bf3, Axp, A1h, A2v, A3v, h3,
                                       b1, b2, b3, bar);

  fc_kernel<<<(64 * 128 * 64 + 255) / 256, 256, 0, stream>>>(h3, fcw, fcb, out);
}

// Round 8
// 4787.382 us; speedup vs baseline: 4.0255x; 2.0640x over previous
//
#include <hip/hip_runtime.h>

typedef _Float16 half8 __attribute__((ext_vector_type(8)));
typedef float f32x4 __attribute__((ext_vector_type(4)));

#define GRIDN 192
#define NTICKS 514
#define TT 512
#define HH 1024

// MFMA, B operand in AGPR ("a") — for the pinned weight units.
#define MFMA_F16_AB(acc_, a_, b_) \
  asm("v_mfma_f32_16x16x32_f16 %0, %1, %2, %0" : "+v"(acc_) : "v"(a_), "a"(b_))
// MFMA, B operand in arch VGPR ("v") — for LDS-staged weight units.
#define MFMA_F16_AV(acc_, a_, b_) \
  asm("v_mfma_f32_16x16x32_f16 %0, %1, %2, %0" : "+v"(acc_) : "v"(a_), "v"(b_))

// Tie-copy a loaded value into an AGPR-class vreg whose DEF is an inline asm
// (non-rematerializable) — keeps the weight slice resident across ticks.
#define PIN_AGPR(dst_, src_) asm("" : "=a"(dst_) : "0"(src_))

__device__ __forceinline__ int kfrag(int l, int j) {
  return ((j >> 2) << 4) + (((l >> 4) & 3) << 2) + (j & 3);
}

__device__ __forceinline__ size_t fragoff(int m, int k, int KBv) {
  int rt = m >> 4, mm = m & 15, kb = k >> 5, kk = k & 31;
  int lp = mm | ((kk & 12) << 2);
  int jp = ((kk >> 4) << 2) | (kk & 3);
  return ((size_t)(rt * KBv + kb) * 512) + (size_t)lp * 8 + jp;
}

__device__ __forceinline__ float sigmoidf_(float x) { return 1.0f / (1.0f + __expf(-x)); }
__device__ __forceinline__ float tanhf_(float x)    { return 2.0f / (1.0f + __expf(-2.0f * x)) - 1.0f; }

// Coherent (agent-scope, L2-bypassing) 16B fragment load as 2x u64 relaxed atomics.
__device__ __forceinline__ half8 ldA(const _Float16* p) {
  union { unsigned long long q[2]; half8 h; } u;
  u.q[0] = __hip_atomic_load((const unsigned long long*)p, __ATOMIC_RELAXED,
                             __HIP_MEMORY_SCOPE_AGENT);
  u.q[1] = __hip_atomic_load((const unsigned long long*)(p + 4), __ATOMIC_RELAXED,
                             __HIP_MEMORY_SCOPE_AGENT);
  return u.h;
}

// ---------------- weight pack: W[k][4096] -> frag layout [cg][kb][gate][lane*8+j] (f16) ---------
__global__ __launch_bounds__(256) void pack_b_kernel(const float* __restrict__ W,
                                                     _Float16* __restrict__ dst, int KB) {
  int e = blockIdx.x * 256 + threadIdx.x;
  int total = 64 * KB * 4 * 512;
  if (e >= total) return;
  int j = e & 7, l = (e >> 3) & 63, nt = (e >> 9) & 3;
  int tmp = e >> 11;
  int kb = tmp % KB, cg = tmp / KB;
  int k = kb * 32 + kfrag(l, j);
  int col = nt * 1024 + cg * 16 + (l & 15);
  dst[e] = (_Float16)W[(size_t)k * 4096 + col];
}

// ---------------- x pack: struct[b][t][d] -> frag layout [t][rt][kb][lane*8+j] (f16) ------------
__global__ __launch_bounds__(256) void pack_x_kernel(const float* __restrict__ x,
                                                     _Float16* __restrict__ dst) {
  int e = blockIdx.x * 256 + threadIdx.x;
  if (e >= TT * 4 * 8 * 512) return;
  int j = e & 7, l = (e >> 3) & 63;
  int tmp = e >> 9;
  int kb = tmp & 7; tmp >>= 3;
  int rt = tmp & 3; int t = tmp >> 2;
  int b = rt * 16 + (l & 15);
  int d = kb * 32 + kfrag(l, j);
  dst[e] = (_Float16)x[((size_t)b * TT + t) * 256 + d];
}

// ---------------- grid barrier: NO cache-wide fences (exchange is sc1-coherent) -----------------
__device__ __forceinline__ void grid_barrier(unsigned* bar, int tick) {
  // drain own sc1 stores (visible at coherence point once vmcnt retires)
  asm volatile("s_waitcnt vmcnt(0)" ::: "memory");
  __syncthreads();
  if (threadIdx.x == 0)
    __hip_atomic_fetch_add(&bar[32 * (blockIdx.x & 7)], 1u, __ATOMIC_RELAXED,
                           __HIP_MEMORY_SCOPE_AGENT);
  if (threadIdx.x < 64) {
    const unsigned target = (unsigned)(tick + 1) * 24u;  // 192/8 arrivals per counter
    for (;;) {
      unsigned v = target;
      if (threadIdx.x < 8)
        v = __hip_atomic_load(&bar[32 * threadIdx.x], __ATOMIC_RELAXED,
                              __HIP_MEMORY_SCOPE_AGENT);
      if (__all(v >= target)) break;
      __builtin_amdgcn_s_sleep(2);
    }
  }
  __syncthreads();
}

// ---------------- persistent pipelined cell loop --------------------------------------------
// 4 warps K-split. Weights: UA units AGPR-pinned + rest LDS (immune to regalloc & caches).
// h-exchange via agent-scope relaxed atomics (sc1) — L2 stays warm, no inv.
template <int CELL, int KBW, int AKB, int UA>
__device__ __forceinline__ void run_cell(float (*red)[16][64][4],
                                         _Float16 (*wlds)[20][512],
                                         const _Float16* __restrict__ Bf,
                                         const _Float16* __restrict__ Ax,
                                         _Float16* Aown, _Float16* Anext,
                                         const float* __restrict__ bias,
                                         float* __restrict__ h3out, unsigned* bar) {
  const int cg   = blockIdx.x & 63;
  const int tid  = threadIdx.x;
  const int warp = tid >> 6;
  const int lane = tid & 63;
  const int KBTOT = (CELL == 0) ? 40 : 64;
  const int kb0   = warp * KBW;

  // elementwise ownership: thread owns (m0,+32) x (colc0, colc0+1); adjacent cols are
  // CONTIGUOUS in frag layout -> one packed u32 atomic store per (m, colpair).
  const int m0    = tid >> 3;          // 0..31
  const int colc0 = (tid & 7) * 2;     // 0,2,..,14
  float bv2[2][4];
#pragma unroll
  for (int j = 0; j < 2; ++j)
#pragma unroll
    for (int g = 0; g < 4; ++g) bv2[j][g] = bias[g * HH + cg * 16 + colc0 + j];

  const _Float16* Bbase = Bf + (size_t)cg * KBTOT * 4 * 512 + (size_t)lane * 8;

  // ---- stage overflow weight units into LDS (once) ----
  if (UA < 4 * KBW) {
#pragma unroll
    for (int u = UA; u < 4 * KBW; ++u) {
      int kk2 = u >> 2, nt2 = u & 3;
      *(half8*)&wlds[warp][u - UA][lane * 8] =
          *(const half8*)(Bbase + ((size_t)(kb0 + kk2) * 4 + nt2) * 512);
    }
  }

  // ---- pin the first UA units in AGPRs ----
  half8 wa[UA];
#pragma unroll
  for (int u = 0; u < UA; ++u) {
    int kk2 = u >> 2, nt2 = u & 3;
    half8 v = *(const half8*)(Bbase + ((size_t)(kb0 + kk2) * 4 + nt2) * 512);
    PIN_AGPR(wa[u], v);
  }

  // ---- persistent cell state in registers: 4 cells/thread ----
  float cs[2][2] = {{0.f, 0.f}, {0.f, 0.f}};
  float hs[2][2] = {{0.f, 0.f}, {0.f, 0.f}};

  for (int tick = 0; tick < NTICKS; ++tick) {
    const int t = tick - CELL;
    if (t >= 0 && t < TT) {
      const int wpar = tick & 1, rpar = wpar ^ 1;
      const _Float16* Ard = Aown + (size_t)rpar * 4 * AKB * 512 + (size_t)lane * 8;
      const _Float16* Axt = Ax + (size_t)t * 4 * 8 * 512 + (size_t)lane * 8;

      auto ldunit = [&](int kk, int rt) -> half8 {
        int kb = kb0 + kk;
        if (CELL == 0 && kb >= 32)
          return *(const half8*)(Axt + ((size_t)rt * 8 + (kb - 32)) * 512);
        return ldA(Ard + ((size_t)rt * AKB + kb) * 512);
      };

      // 4-ahead A prefetch, ring of 6 (all indices compile-time)
      half8 av[6][4];
#pragma unroll
      for (int p = 0; p < 4; ++p)
#pragma unroll
        for (int rt = 0; rt < 4; ++rt) av[p][rt] = ldunit(p, rt);

      f32x4 acc[4][4];
#pragma unroll
      for (int a = 0; a < 4; ++a)
#pragma unroll
        for (int b2 = 0; b2 < 4; ++b2) acc[a][b2] = (f32x4){0.f, 0.f, 0.f, 0.f};

#pragma unroll
      for (int kk = 0; kk < KBW; ++kk) {
        if (kk + 4 < KBW) {
#pragma unroll
          for (int rt = 0; rt < 4; ++rt) av[(kk + 4) % 6][rt] = ldunit(kk + 4, rt);
        }
#pragma unroll
        for (int nt = 0; nt < 4; ++nt) {
          const int u = kk * 4 + nt;
          if (u < UA) {
#pragma unroll
            for (int rt = 0; rt < 4; ++rt)
              MFMA_F16_AB(acc[rt][nt], av[kk % 6][rt], wa[u < UA ? u : 0]);
          } else {
            half8 b = *(const half8*)&wlds[warp][(u >= UA ? u - UA : 0)][lane * 8];
#pragma unroll
            for (int rt = 0; rt < 4; ++rt)
              MFMA_F16_AV(acc[rt][nt], av[kk % 6][rt], b);
          }
        }
      }
      // guard asm-MFMA -> DS read-after-write
      asm volatile("s_nop 7\n\ts_nop 7");

      // K-split reduction across the 4 warps via LDS
#pragma unroll
      for (int rt = 0; rt < 4; ++rt)
#pragma unroll
        for (int nt = 0; nt < 4; ++nt)
          *(f32x4*)&red[warp][rt * 4 + nt][lane][0] = acc[rt][nt];
      __syncthreads();

      // elementwise: 4 cells/thread (2 m x 2 adjacent cols), state in registers
#pragma unroll
      for (int e = 0; e < 2; ++e) {
        const int m = m0 + e * 32;
        const int rt4 = (m >> 4) * 4, lc_hi = ((m & 15) >> 2) << 4, rr = m & 3;
        float hnf[2];
        union { _Float16 h[2]; unsigned u; } pk;
#pragma unroll
        for (int j = 0; j < 2; ++j) {
          const int lc = (colc0 + j) | lc_hi;
          float pre[4];
#pragma unroll
          for (int g = 0; g < 4; ++g)
            pre[g] = red[0][rt4 + g][lc][rr] + red[1][rt4 + g][lc][rr] +
                     red[2][rt4 + g][lc][rr] + red[3][rt4 + g][lc][rr] + bv2[j][g];
          float sf = sigmoidf_(pre[0]), si = sigmoidf_(pre[1]), so = sigmoidf_(pre[2]);
          float tg = tanhf_(pre[3]);
          float c_old = cs[e][j], h_old = hs[e][j];
          float c0 = sf * c_old + si * tg;
          float h0 = so * tanhf_(c0);
          float cn = 0.9f * c0 + 0.1f * c_old;
          float hn = 0.9f * h0 + 0.1f * h_old;
          cs[e][j] = cn;
          hs[e][j] = hn;
          hnf[j] = hn;
          pk.h[j] = (_Float16)hn;
        }
        const int hcol0 = cg * 16 + colc0;
        {
          size_t off = (size_t)wpar * 4 * AKB * 512 + fragoff(m, hcol0, AKB);
          __hip_atomic_store((unsigned*)(Aown + off), pk.u, __ATOMIC_RELAXED,
                             __HIP_MEMORY_SCOPE_AGENT);
        }
        if (CELL < 2) {
          size_t off = (size_t)wpar * 4 * 64 * 512 + fragoff(m, 1024 + hcol0, 64);
          __hip_atomic_store((unsigned*)(Anext + off), pk.u, __ATOMIC_RELAXED,
                             __HIP_MEMORY_SCOPE_AGENT);
        }
        if (CELL == 2 && t == TT - 1) {
          h3out[m * HH + hcol0]     = hnf[0];
          h3out[m * HH + hcol0 + 1] = hnf[1];
        }
      }
    }

    if (tick < NTICKS - 1) grid_barrier(bar, tick);
  }
}

__global__ __launch_bounds__(256, 1) void lstm_coop(
    const _Float16* __restrict__ Bf1, const _Float16* __restrict__ Bf2,
    const _Float16* __restrict__ Bf3, const _Float16* __restrict__ Ax,
    _Float16* A1h, _Float16* A2v, _Float16* A3v, float* h3,
    const float* __restrict__ bb1, const float* __restrict__ bb2, const float* __restrict__ bb3,
    unsigned* bar) {
  __shared__ float red[4][16][64][4];        // 64 KiB exchange
  __shared__ _Float16 wlds[4][20][512];      // 80 KiB LDS-resident weight units
  const int cell = blockIdx.x >> 6;
  if (cell == 0)
    run_cell<0, 10, 32, 40>(red, wlds, Bf1, Ax, A1h, A2v, bb1, nullptr, bar);
  else if (cell == 1)
    run_cell<1, 16, 64, 44>(red, wlds, Bf2, Ax, A2v, A3v, bb2, nullptr, bar);
  else
    run_cell<2, 16, 64, 44>(red, wlds, Bf3, Ax, A3v, nullptr, bb3, h3, bar);
}

// ---------------- final FC + ELU ----------------------------------------------------------------
__global__ __launch_bounds__(256) void fc_kernel(const float* __restrict__ h3,
                                                 const float* __restrict__ fcw,
                                                 const float* __restrict__ fcb,
                                                 float* __restrict__ out) {
  int wid = (blockIdx.x * 256 + threadIdx.x) >> 6;
  int lane = threadIdx.x & 63;
  if (wid >= 64 * 128) return;
  int b = wid >> 7, cc = wid & 127;
  float s = 0.f;
#pragma unroll
  for (int i = 0; i < 16; ++i) {
    int k = i * 64 + lane;
    s += h3[b * HH + k] * fcw[cc * HH + k];
  }
#pragma unroll
  for (int o = 32; o; o >>= 1) s += __shfl_xor(s, o, 64);
  if (lane == 0) {
    s += fcb[cc];
    out[b * 128 + cc] = s > 0.f ? s : (__expf(s) - 1.0f);
  }
}

extern "C" void kernel_launch(void* const* d_in, const int* in_sizes, int n_in,
                              void* d_out, int out_size, void* d_ws, size_t ws_size,
                              hipStream_t stream) {
  const float* xs  = (const float*)d_in[0];
  const float* W1  = (const float*)d_in[1];
  const float* b1  = (const float*)d_in[2];
  const float* W2  = (const float*)d_in[3];
  const float* b2  = (const float*)d_in[4];
  const float* W3  = (const float*)d_in[5];
  const float* b3  = (const float*)d_in[6];
  const float* fcw = (const float*)d_in[7];
  const float* fcb = (const float*)d_in[8];
  float* out = (float*)d_out;

  char* p = (char*)d_ws;
  auto alloc = [&](size_t bytes) {
    char* r = p;
    p += (bytes + 255) & ~(size_t)255;
    return r;
  };

  // ---- zero-init region (re-zeroed every replay) ----
  char* zbase = p;
  _Float16* A1h = (_Float16*)alloc((size_t)2 * 4 * 32 * 512 * 2);
  _Float16* A2v = (_Float16*)alloc((size_t)2 * 4 * 64 * 512 * 2);
  _Float16* A3v = (_Float16*)alloc((size_t)2 * 4 * 64 * 512 * 2);
  unsigned* bar = (unsigned*)alloc(1024);
  size_t zbytes = (size_t)(p - zbase);

  // ---- fully-overwritten region ----
  float* h3 = (float*)alloc((size_t)64 * 1024 * 4);
  _Float16* Bf1 = (_Float16*)alloc((size_t)64 * 40 * 4 * 512 * 2);
  _Float16* Bf2 = (_Float16*)alloc((size_t)64 * 64 * 4 * 512 * 2);
  _Float16* Bf3 = (_Float16*)alloc((size_t)64 * 64 * 4 * 512 * 2);
  _Float16* Axp = (_Float16*)alloc((size_t)TT * 4 * 8 * 512 * 2);

  (void)hipMemsetAsync(zbase, 0, zbytes, stream);

  {
    int tot1 = 64 * 40 * 4 * 512, tot23 = 64 * 64 * 4 * 512;
    pack_b_kernel<<<(tot1 + 255) / 256, 256, 0, stream>>>(W1, Bf1, 40);
    pack_b_kernel<<<(tot23 + 255) / 256, 256, 0, stream>>>(W2, Bf2, 64);
    pack_b_kernel<<<(tot23 + 255) / 256, 256, 0, stream>>>(W3, Bf3, 64);
    int totx = TT * 4 * 8 * 512;
    pack_x_kernel<<<(totx + 255) / 256, 256, 0, stream>>>(xs, Axp);
  }

  lstm_coop<<<GRIDN, 256, 0, stream>>>(Bf1, Bf2, Bf3, Axp, A1h, A2v, A3v, h3,
                                       b1, b2, b3, bar);

  fc_kernel<<<(64 * 128 * 64 + 255) / 256, 256, 0, stream>>>(h3, fcw, fcb, out);
}

// Round 11
// 3895.998 us; speedup vs baseline: 4.9465x; 1.2288x over previous
//
#include <hip/hip_runtime.h>

typedef _Float16 half8 __attribute__((ext_vector_type(8)));
typedef float f32x4 __attribute__((ext_vector_type(4)));

#define GRIDN 192
#define NTICKS 514
#define TT 512
#define HH 1024

// MFMA, B operand in AGPR ("a") — for the pinned weight units.
#define MFMA_F16_AB(acc_, a_, b_) \
  asm("v_mfma_f32_16x16x32_f16 %0, %1, %2, %0" : "+v"(acc_) : "v"(a_), "a"(b_))
// MFMA, B operand in arch VGPR ("v") — for LDS-staged weight units.
#define MFMA_F16_AV(acc_, a_, b_) \
  asm("v_mfma_f32_16x16x32_f16 %0, %1, %2, %0" : "+v"(acc_) : "v"(a_), "v"(b_))

// Tie-copy a loaded value into an AGPR-class vreg whose DEF is an inline asm
// (non-rematerializable) — keeps the weight slice resident across ticks.
#define PIN_AGPR(dst_, src_) asm("" : "=a"(dst_) : "0"(src_))

__device__ __forceinline__ int kfrag(int l, int j) {
  return ((j >> 2) << 4) + (((l >> 4) & 3) << 2) + (j & 3);
}

__device__ __forceinline__ size_t fragoff(int m, int k, int KBv) {
  int rt = m >> 4, mm = m & 15, kb = k >> 5, kk = k & 31;
  int lp = mm | ((kk & 12) << 2);
  int jp = ((kk >> 4) << 2) | (kk & 3);
  return ((size_t)(rt * KBv + kb) * 512) + (size_t)lp * 8 + jp;
}

__device__ __forceinline__ float sigmoidf_(float x) { return 1.0f / (1.0f + __expf(-x)); }
__device__ __forceinline__ float tanhf_(float x)    { return 2.0f / (1.0f + __expf(-2.0f * x)) - 1.0f; }

// ---------------- weight pack: W[k][4096] -> frag layout [cg][kb][gate][lane*8+j] (f16) ---------
__global__ __launch_bounds__(256) void pack_b_kernel(const float* __restrict__ W,
                                                     _Float16* __restrict__ dst, int KB) {
  int e = blockIdx.x * 256 + threadIdx.x;
  int total = 64 * KB * 4 * 512;
  if (e >= total) return;
  int j = e & 7, l = (e >> 3) & 63, nt = (e >> 9) & 3;
  int tmp = e >> 11;
  int kb = tmp % KB, cg = tmp / KB;
  int k = kb * 32 + kfrag(l, j);
  int col = nt * 1024 + cg * 16 + (l & 15);
  dst[e] = (_Float16)W[(size_t)k * 4096 + col];
}

// ---------------- x pack: struct[b][t][d] -> frag layout [t][rt][kb][lane*8+j] (f16) ------------
__global__ __launch_bounds__(256) void pack_x_kernel(const float* __restrict__ x,
                                                     _Float16* __restrict__ dst) {
  int e = blockIdx.x * 256 + threadIdx.x;
  if (e >= TT * 4 * 8 * 512) return;
  int j = e & 7, l = (e >> 3) & 63;
  int tmp = e >> 9;
  int kb = tmp & 7; tmp >>= 3;
  int rt = tmp & 3; int t = tmp >> 2;
  int b = rt * 16 + (l & 15);
  int d = kb * 32 + kfrag(l, j);
  dst[e] = (_Float16)x[((size_t)b * TT + t) * 256 + d];
}

// ---------------- grid barrier: 8 padded monotonic counters, leaderless, NO cache fences --------
__device__ __forceinline__ void grid_barrier(unsigned* bar, int tick) {
  asm volatile("s_waitcnt vmcnt(0)" ::: "memory");  // drain own write-through stores
  __syncthreads();
  if (threadIdx.x == 0)
    __hip_atomic_fetch_add(&bar[32 * (blockIdx.x & 7)], 1u, __ATOMIC_RELAXED,
                           __HIP_MEMORY_SCOPE_AGENT);
  if (threadIdx.x < 64) {
    const unsigned target = (unsigned)(tick + 1) * 24u;  // 192/8 arrivals per counter
    for (;;) {
      unsigned v = target;
      if (threadIdx.x < 8)
        v = __hip_atomic_load(&bar[32 * threadIdx.x], __ATOMIC_RELAXED,
                              __HIP_MEMORY_SCOPE_AGENT);
      if (__all(v >= target)) break;
      __builtin_amdgcn_s_sleep(2);
    }
  }
  __syncthreads();
}

// ---------------- persistent pipelined cell loop --------------------------------------------
// r8-proven protocol. A-loads: 16B bypass-coherent asm loads (sc0 sc1), software-pipelined
// 7 steps ahead with counted vmcnt + sched_barrier (rule #18).
template <int CELL, int KBW, int AKB, int UA>
__device__ __forceinline__ void run_cell(float (*red)[16][64][4],
                                         _Float16 (*wlds)[20][512],
                                         const _Float16* __restrict__ Bf,
                                         const _Float16* __restrict__ Ax,
                                         _Float16* Aown, _Float16* Anext,
                                         const float* __restrict__ bias,
                                         float* __restrict__ h3out, unsigned* bar) {
  const int cg   = blockIdx.x & 63;
  const int tid  = threadIdx.x;
  const int warp = tid >> 6;
  const int lane = tid & 63;
  const int KBTOT = (CELL == 0) ? 40 : 64;
  const int kb0   = warp * KBW;

  const int m0    = tid >> 3;          // 0..31
  const int colc0 = (tid & 7) * 2;     // 0,2,..,14
  float bv2[2][4];
#pragma unroll
  for (int j = 0; j < 2; ++j)
#pragma unroll
    for (int g = 0; g < 4; ++g) bv2[j][g] = bias[g * HH + cg * 16 + colc0 + j];

  const _Float16* Bbase = Bf + (size_t)cg * KBTOT * 4 * 512 + (size_t)lane * 8;

  // ---- stage overflow weight units into LDS (once) ----
  if (UA < 4 * KBW) {
#pragma unroll
    for (int u = UA; u < 4 * KBW; ++u) {
      int kk2 = u >> 2, nt2 = u & 3;
      *(half8*)&wlds[warp][u - UA][lane * 8] =
          *(const half8*)(Bbase + ((size_t)(kb0 + kk2) * 4 + nt2) * 512);
    }
  }

  // ---- pin the first UA units in AGPRs ----
  half8 wa[UA];
#pragma unroll
  for (int u = 0; u < UA; ++u) {
    int kk2 = u >> 2, nt2 = u & 3;
    half8 v = *(const half8*)(Bbase + ((size_t)(kb0 + kk2) * 4 + nt2) * 512);
    PIN_AGPR(wa[u], v);
  }

  // ---- persistent cell state in registers: 4 cells/thread ----
  float cs[2][2] = {{0.f, 0.f}, {0.f, 0.f}};
  float hs[2][2] = {{0.f, 0.f}, {0.f, 0.f}};

  for (int tick = 0; tick < NTICKS; ++tick) {
    const int t = tick - CELL;
    if (t >= 0 && t < TT) {
      const int wpar = tick & 1, rpar = wpar ^ 1;
      const _Float16* Ard = Aown + (size_t)rpar * 4 * AKB * 512 + (size_t)lane * 8;
      const _Float16* Axt = Ax + (size_t)t * 4 * 8 * 512 + (size_t)lane * 8;

      auto aptr = [&](int kk, int rt) -> const _Float16* {
        int kb = kb0 + kk;
        if (CELL == 0 && kb >= 32) return Axt + ((size_t)rt * 8 + (kb - 32)) * 512;
        return Ard + ((size_t)rt * AKB + kb) * 512;
      };

      half8 av[8][4];  // ring of 8, 7 steps in flight
      f32x4 acc[4][4];
#pragma unroll
      for (int a = 0; a < 4; ++a)
#pragma unroll
        for (int b2 = 0; b2 < 4; ++b2) acc[a][b2] = (f32x4){0.f, 0.f, 0.f, 0.f};

// issue 4 bypass-coherent 16B loads for K-step kk (in-order issue => vmcnt accounting holds)
#define ISSUE4(kk)                                                    \
  {                                                                   \
    _Pragma("unroll") for (int rt = 0; rt < 4; ++rt)                  \
        asm volatile("global_load_dwordx4 %0, %1, off sc0 sc1"        \
                     : "=v"(av[(kk) & 7][rt])                         \
                     : "v"(aptr((kk), rt)));                          \
  }

// one K-step: refill 7-ahead, counted wait for step kk, pin scheduler, 16 MFMAs
#define STEP(kk)                                                               \
  if constexpr ((kk) < KBW) {                                                  \
    if constexpr ((kk) + 7 < KBW) ISSUE4((kk) + 7);                            \
    asm volatile("s_waitcnt vmcnt(%0)" ::                                      \
                     "n"((kk) + 7 < KBW ? 28 : (KBW - 1 - (kk)) * 4)           \
                 : "memory");                                                  \
    __builtin_amdgcn_sched_barrier(0);                                         \
    _Pragma("unroll") for (int nt = 0; nt < 4; ++nt) {                         \
      const int u = (kk)*4 + nt;                                               \
      if (u < UA) {                                                            \
        _Pragma("unroll") for (int rt = 0; rt < 4; ++rt)                       \
            MFMA_F16_AB(acc[rt][nt], av[(kk) & 7][rt], wa[u < UA ? u : 0]);    \
      } else {                                                                 \
        half8 bw =                                                             \
            *(const half8*)&wlds[warp][(u >= UA ? u - UA : 0)][lane * 8];      \
        _Pragma("unroll") for (int rt = 0; rt < 4; ++rt)                       \
            MFMA_F16_AV(acc[rt][nt], av[(kk) & 7][rt], bw);                    \
      }                                                                        \
    }                                                                          \
  }

      // prologue: 7 steps in flight
      ISSUE4(0); ISSUE4(1); ISSUE4(2); ISSUE4(3); ISSUE4(4); ISSUE4(5); ISSUE4(6);
      STEP(0)  STEP(1)  STEP(2)  STEP(3)  STEP(4)  STEP(5)  STEP(6)  STEP(7)
      STEP(8)  STEP(9)  STEP(10) STEP(11) STEP(12) STEP(13) STEP(14) STEP(15)
#undef ISSUE4
#undef STEP

      // guard asm-MFMA -> DS read-after-write
      asm volatile("s_nop 7\n\ts_nop 7");

      // K-split reduction across the 4 warps via LDS
#pragma unroll
      for (int rt = 0; rt < 4; ++rt)
#pragma unroll
        for (int nt = 0; nt < 4; ++nt)
          *(f32x4*)&red[warp][rt * 4 + nt][lane][0] = acc[rt][nt];
      __syncthreads();

      // elementwise: 4 cells/thread (2 m x 2 adjacent cols), state in registers
#pragma unroll
      for (int e = 0; e < 2; ++e) {
        const int m = m0 + e * 32;
        const int rt4 = (m >> 4) * 4, lc_hi = ((m & 15) >> 2) << 4, rr = m & 3;
        float hnf[2];
        union { _Float16 h[2]; unsigned u; } pk;
#pragma unroll
        for (int j = 0; j < 2; ++j) {
          const int lc = (colc0 + j) | lc_hi;
          float pre[4];
#pragma unroll
          for (int g = 0; g < 4; ++g)
            pre[g] = red[0][rt4 + g][lc][rr] + red[1][rt4 + g][lc][rr] +
                     red[2][rt4 + g][lc][rr] + red[3][rt4 + g][lc][rr] + bv2[j][g];
          float sf = sigmoidf_(pre[0]), si = sigmoidf_(pre[1]), so = sigmoidf_(pre[2]);
          float tg = tanhf_(pre[3]);
          float c_old = cs[e][j], h_old = hs[e][j];
          float c0 = sf * c_old + si * tg;
          float h0 = so * tanhf_(c0);
          float cn = 0.9f * c0 + 0.1f * c_old;
          float hn = 0.9f * h0 + 0.1f * h_old;
          cs[e][j] = cn;
          hs[e][j] = hn;
          hnf[j] = hn;
          pk.h[j] = (_Float16)hn;
        }
        const int hcol0 = cg * 16 + colc0;
        {
          size_t off = (size_t)wpar * 4 * AKB * 512 + fragoff(m, hcol0, AKB);
          __hip_atomic_store((unsigned*)(Aown + off), pk.u, __ATOMIC_RELAXED,
                             __HIP_MEMORY_SCOPE_AGENT);
        }
        if (CELL < 2) {
          size_t off = (size_t)wpar * 4 * 64 * 512 + fragoff(m, 1024 + hcol0, 64);
          __hip_atomic_store((unsigned*)(Anext + off), pk.u, __ATOMIC_RELAXED,
                             __HIP_MEMORY_SCOPE_AGENT);
        }
        if (CELL == 2 && t == TT - 1) {
          h3out[m * HH + hcol0]     = hnf[0];
          h3out[m * HH + hcol0 + 1] = hnf[1];
        }
      }
    }

    if (tick < NTICKS - 1) grid_barrier(bar, tick);
  }
}

__global__ __launch_bounds__(256, 1) void lstm_coop(
    const _Float16* __restrict__ Bf1, const _Float16* __restrict__ Bf2,
    const _Float16* __restrict__ Bf3, const _Float16* __restrict__ Ax,
    _Float16* A1h, _Float16* A2v, _Float16* A3v, float* h3,
    const float* __restrict__ bb1, const float* __restrict__ bb2, const float* __restrict__ bb3,
    unsigned* bar) {
  __shared__ float red[4][16][64][4];        // 64 KiB exchange
  __shared__ _Float16 wlds[4][20][512];      // 80 KiB LDS-resident weight units
  const int cell = blockIdx.x >> 6;
  if (cell == 0)
    run_cell<0, 10, 32, 40>(red, wlds, Bf1, Ax, A1h, A2v, bb1, nullptr, bar);
  else if (cell == 1)
    run_cell<1, 16, 64, 44>(red, wlds, Bf2, Ax, A2v, A3v, bb2, nullptr, bar);
  else
    run_cell<2, 16, 64, 44>(red, wlds, Bf3, Ax, A3v, nullptr, bb3, h3, bar);
}

// ---------------- final FC + ELU ----------------------------------------------------------------
__global__ __launch_bounds__(256) void fc_kernel(const float* __restrict__ h3,
                                                 const float* __restrict__ fcw,
                                                 const float* __restrict__ fcb,
                                                 float* __restrict__ out) {
  int wid = (blockIdx.x * 256 + threadIdx.x) >> 6;
  int lane = threadIdx.x & 63;
  if (wid >= 64 * 128) return;
  int b = wid >> 7, cc = wid & 127;
  float s = 0.f;
#pragma unroll
  for (int i = 0; i < 16; ++i) {
    int k = i * 64 + lane;
    s += h3[b * HH + k] * fcw[cc * HH + k];
  }
#pragma unroll
  for (int o = 32; o; o >>= 1) s += __shfl_xor(s, o, 64);
  if (lane == 0) {
    s += fcb[cc];
    out[b * 128 + cc] = s > 0.f ? s : (__expf(s) - 1.0f);
  }
}

extern "C" void kernel_launch(void* const* d_in, const int* in_sizes, int n_in,
                              void* d_out, int out_size, void* d_ws, size_t ws_size,
                              hipStream_t stream) {
  const float* xs  = (const float*)d_in[0];
  const float* W1  = (const float*)d_in[1];
  const float* b1  = (const float*)d_in[2];
  const float* W2  = (const float*)d_in[3];
  const float* b2  = (const float*)d_in[4];
  const float* W3  = (const float*)d_in[5];
  const float* b3  = (const float*)d_in[6];
  const float* fcw = (const float*)d_in[7];
  const float* fcb = (const float*)d_in[8];
  float* out = (float*)d_out;

  char* p = (char*)d_ws;
  auto alloc = [&](size_t bytes) {
    char* r = p;
    p += (bytes + 255) & ~(size_t)255;
    return r;
  };

  // ---- zero-init region (re-zeroed every replay) ----
  char* zbase = p;
  _Float16* A1h = (_Float16*)alloc((size_t)2 * 4 * 32 * 512 * 2);
  _Float16* A2v = (_Float16*)alloc((size_t)2 * 4 * 64 * 512 * 2);
  _Float16* A3v = (_Float16*)alloc((size_t)2 * 4 * 64 * 512 * 2);
  unsigned* bar = (unsigned*)alloc(1024);
  size_t zbytes = (size_t)(p - zbase);

  // ---- fully-overwritten region ----
  float* h3 = (float*)alloc((size_t)64 * 1024 * 4);
  _Float16* Bf1 = (_Float16*)alloc((size_t)64 * 40 * 4 * 512 * 2);
  _Float16* Bf2 = (_Float16*)alloc((size_t)64 * 64 * 4 * 512 * 2);
  _Float16* Bf3 = (_Float16*)alloc((size_t)64 * 64 * 4 * 512 * 2);
  _Float16* Axp = (_Float16*)alloc((size_t)TT * 4 * 8 * 512 * 2);

  (void)hipMemsetAsync(zbase, 0, zbytes, stream);

  {
    int tot1 = 64 * 40 * 4 * 512, tot23 = 64 * 64 * 4 * 512;
    pack_b_kernel<<<(tot1 + 255) / 256, 256, 0, stream>>>(W1, Bf1, 40);
    pack_b_kernel<<<(tot23 + 255) / 256, 256, 0, stream>>>(W2, Bf2, 64);
    pack_b_kernel<<<(tot23 + 255) / 256, 256, 0, stream>>>(W3, Bf3, 64);
    int totx = TT * 4 * 8 * 512;
    pack_x_kernel<<<(totx + 255) / 256, 256, 0, stream>>>(xs, Axp);
  }

  lstm_coop<<<GRIDN, 256, 0, stream>>>(Bf1, Bf2, Bf3, Axp, A1h, A2v, A3v, h3,
                                       b1, b2, b3, bar);

  fc_kernel<<<(64 * 128 * 64 + 255) / 256, 256, 0, stream>>>(h3, fcw, fcb, out);
}